// Round 13
// baseline (289.120 us; speedup 1.0000x reference)
//
#include <hip/hip_runtime.h>
#include <hip/hip_bf16.h>
#include <stdint.h>

// B=4, C=512, H=W=64 -> N=4096. Channel-first x [B,C,N].
#define C_DIM 512
#define N_DIM 4096
#define B_DIM 4

typedef __bf16 bf16x8 __attribute__((ext_vector_type(8)));
typedef float f32x4 __attribute__((ext_vector_type(4)));
typedef int i32x8 __attribute__((ext_vector_type(8)));
#define AS1 __attribute__((address_space(1)))
#define AS3 __attribute__((address_space(3)))

static __device__ __forceinline__ unsigned short f2bf(float x) {
  unsigned u = __float_as_uint(x);
  unsigned r = (u + 0x7fffu + ((u >> 16) & 1u)) >> 16;
  return (unsigned short)r;
}
static __device__ __forceinline__ unsigned char f2fp8(float x) {
  return (unsigned char)__builtin_amdgcn_cvt_pk_fp8_f32(x, x, 0, false);
}

__global__ __launch_bounds__(256) void cvt_weights(
    const float* __restrict__ w0, const float* __restrict__ w1,
    const float* __restrict__ w2, const float* __restrict__ w3,
    unsigned short* __restrict__ o0, unsigned short* __restrict__ o1,
    unsigned short* __restrict__ o2, unsigned short* __restrict__ o3) {
  int i = blockIdx.x * blockDim.x + threadIdx.x;
  if (i < C_DIM * C_DIM) {
    o0[i] = f2bf(w0[i]); o1[i] = f2bf(w1[i]);
    o2[i] = f2bf(w2[i]); o3[i] = f2bf(w3[i]);
  }
}

// x [B,C,N] f32 -> Xt [B,N,C] bf16
__global__ __launch_bounds__(256) void transpose_x(
    const float* __restrict__ x, unsigned short* __restrict__ Xt) {
  __shared__ float t[32][33];
  const int b = blockIdx.z;
  const float* xb = x + (size_t)b * C_DIM * N_DIM;
  unsigned short* xtb = Xt + (size_t)b * N_DIM * C_DIM;
  const int n0 = blockIdx.x * 32, c0 = blockIdx.y * 32;
  const int tx = threadIdx.x, ty = threadIdx.y;
  #pragma unroll
  for (int i = ty; i < 32; i += 8)
    t[i][tx] = xb[(size_t)(c0 + i) * N_DIM + n0 + tx];
  __syncthreads();
  #pragma unroll
  for (int i = ty; i < 32; i += 8)
    xtb[(size_t)(n0 + i) * C_DIM + c0 + tx] = f2bf(t[tx][i]);
}

__global__ __launch_bounds__(256) void zero_buf(float* __restrict__ p, int n) {
  int i = blockIdx.x * 256 + threadIdx.x;
  if (i < n) p[i] = 0.f;
}

// ---------------- 128^2-tile 2-phase NT GEMM body (bf16 inputs) ------------
template<int BIAS, int OUT8>
__device__ __forceinline__ void gemm128_body(
    unsigned short* As, unsigned short* Bs,
    const unsigned short* __restrict__ A, const unsigned short* __restrict__ B,
    void* __restrict__ Cv, int K, int ldc,
    const float* __restrict__ bias, int bx, int by) {
  const int tid = threadIdx.x;
  const int wid = tid >> 6, lane = tid & 63;
  const int wm = (wid >> 1) * 64, wn = (wid & 1) * 64;
  f32x4 acc[4][4] = {};
  const size_t rowA0 = (size_t)bx * 128;
  const size_t rowB0 = (size_t)by * 128;
  const int sgrp = wid * 2;
  const int r0 = (sgrp * 64 + lane) >> 2;
  const int r1 = ((sgrp + 1) * 64 + lane) >> 2;
  const int cc = ((lane & 3) ^ ((lane >> 3) & 3)) * 8;
  const int lr = lane & 15;
  const int koff = (((lane >> 4) ^ ((lr >> 1) & 3))) * 8;

  for (int k0 = 0; k0 < K; k0 += 32) {
    __syncthreads();
    __builtin_amdgcn_global_load_lds(
        (const AS1 void*)(A + (rowA0 + r0) * K + k0 + cc),
        (AS3 void*)(As + sgrp * 512), 16, 0, 0);
    __builtin_amdgcn_global_load_lds(
        (const AS1 void*)(A + (rowA0 + r1) * K + k0 + cc),
        (AS3 void*)(As + (sgrp + 1) * 512), 16, 0, 0);
    __builtin_amdgcn_global_load_lds(
        (const AS1 void*)(B + (rowB0 + r0) * K + k0 + cc),
        (AS3 void*)(Bs + sgrp * 512), 16, 0, 0);
    __builtin_amdgcn_global_load_lds(
        (const AS1 void*)(B + (rowB0 + r1) * K + k0 + cc),
        (AS3 void*)(Bs + (sgrp + 1) * 512), 16, 0, 0);
    __syncthreads();
    bf16x8 af[4], bf[4];
    #pragma unroll
    for (int m = 0; m < 4; ++m)
      af[m] = *reinterpret_cast<const bf16x8*>(&As[(wm + m * 16 + lr) * 32 + koff]);
    #pragma unroll
    for (int n = 0; n < 4; ++n)
      bf[n] = *reinterpret_cast<const bf16x8*>(&Bs[(wn + n * 16 + lr) * 32 + koff]);
    #pragma unroll
    for (int m = 0; m < 4; ++m)
      #pragma unroll
      for (int n = 0; n < 4; ++n)
        acc[m][n] = __builtin_amdgcn_mfma_f32_16x16x32_bf16(af[m], bf[n], acc[m][n], 0, 0, 0);
  }

  const int rg = (lane >> 4) * 4;
  #pragma unroll
  for (int m = 0; m < 4; ++m) {
    #pragma unroll
    for (int n = 0; n < 4; ++n) {
      const int col = (int)rowB0 + wn + n * 16 + lr;
      #pragma unroll
      for (int r = 0; r < 4; ++r) {
        int row = (int)rowA0 + wm + m * 16 + rg + r;
        float v = acc[m][n][r];
        if (BIAS == 1) v += bias[col];
        if (OUT8)
          ((unsigned char*)Cv)[(size_t)row * ldc + col] = f2fp8(v);
        else
          ((unsigned short*)Cv)[(size_t)row * ldc + col] = f2bf(v);
      }
    }
  }
}

// merged Q,K,V projections: grid (32, 4, 12); z = wsel + 3*batch
__global__ __launch_bounds__(256, 2) void gemm_qkv(
    const unsigned short* __restrict__ Xt,
    const unsigned short* __restrict__ Wq, const unsigned short* __restrict__ Wk,
    const unsigned short* __restrict__ Wv,
    const float* __restrict__ bq, const float* __restrict__ bk,
    const float* __restrict__ bv,
    unsigned char* __restrict__ Qb, unsigned char* __restrict__ Kb,
    unsigned short* __restrict__ Vb) {
  __shared__ unsigned short As[4096], Bs[4096];
  const long NCe = (long)N_DIM * C_DIM;
  const int z = blockIdx.z;
  const int wsel = z % 3, bat = z / 3;
  const unsigned short* Xz = Xt + (size_t)bat * NCe;
  if (wsel == 0) {
    gemm128_body<1, 1>(As, Bs, Xz, Wq, Qb + (size_t)bat * NCe, C_DIM, C_DIM,
                       bq, blockIdx.x, blockIdx.y);
  } else if (wsel == 1) {
    gemm128_body<1, 1>(As, Bs, Xz, Wk, Kb + (size_t)bat * NCe, C_DIM, C_DIM,
                       bk, blockIdx.x, blockIdx.y);
  } else {
    gemm128_body<1, 0>(As, Bs, Xz, Wv, Vb + (size_t)bat * NCe, C_DIM, C_DIM,
                       bv, blockIdx.x, blockIdx.y);
  }
}

// PVt[o,j] = sum_c Wp[o,c] V[j,c] -> fp8; grid (4, 32, 4)
__global__ __launch_bounds__(256, 2) void gemm_pvt(
    const unsigned short* __restrict__ Wp, const unsigned short* __restrict__ Vb,
    unsigned char* __restrict__ PVt) {
  __shared__ unsigned short As[4096], Bs[4096];
  const long NCe = (long)N_DIM * C_DIM;
  const long PVe = (long)C_DIM * N_DIM;
  const int z = blockIdx.z;
  gemm128_body<0, 1>(As, Bs, Wp, Vb + (size_t)z * NCe, PVt + (size_t)z * PVe,
                     C_DIM, N_DIM, nullptr, blockIdx.x, blockIdx.y);
}

// ---------------- MX-fp8 NT GEMM (m97 structure, K-step 128) ----------------
// A,B fp8 e4m3 row-major NT. 256 thr = 4 waves (2x2). M-tile = MFR*32
// (per-wave MFR m-frags x 64 cols), B-tile 128. acc[MFR][4].
// mfma_scale_f32_16x16x128_f8f6f4, scale=1.0 (e8m0 127) = exact fp8 math at
// 2x bf16 rate. Single-buffered 2-phase; 4 blocks/CU declared
// (__launch_bounds__(256,4)) for cross-block stage/compute overlap (m114).
// Swizzle: phys 16B slot p of row r holds global slot p ^ (r&7) (fp8 row =
// 128 B = full bank period); staged via pre-swizzled global source (linear
// gload_lds dest). Frag reads land directly in i32x8 halves (no repack).
// A-frag: lane l holds row l&15, k = (l>>4)*32..+31 (two b128) [verified R12].
// MODE 0: store fp8 exp(scale*acc); f32 rowsums -> atomicAdd denom[row].
// MODE 1: store f32 acc/denom[col] + bias[row] + resid  (final output).
template<int MFR, int MODE, int GX, int GY>
__global__ __launch_bounds__(256, 4) void gemm_mx(
    const unsigned char* __restrict__ A, long sA,
    const unsigned char* __restrict__ B, long sB,
    void* __restrict__ Cp, long sC,
    int K, int lda, int ldb, int ldc, float scale,
    const float* __restrict__ bias,
    float* __restrict__ denom, long sDen,
    const float* __restrict__ resid, long sR) {
  constexpr int MT = MFR * 32;           // block M-tile rows
  constexpr int WM = MFR * 16;           // per-wave M rows
  __shared__ unsigned char Asm[MT * 128], Bsm[16384];

  // XCD-aware bijective block swizzle (nwg % 8 == 0 at all call sites)
  int flat = blockIdx.x + GX * (blockIdx.y + GY * blockIdx.z);
  const int nwg = GX * GY * gridDim.z;
  flat = (flat & 7) * (nwg >> 3) + (flat >> 3);
  const int bx = flat & (GX - 1);
  const int by = (flat / GX) & (GY - 1);
  const int z  = flat / (GX * GY);

  const unsigned char* Ag = A + (size_t)z * sA + (size_t)bx * MT * lda;
  const unsigned char* Bg = B + (size_t)z * sB + (size_t)by * 128 * ldb;
  const int tid = threadIdx.x;
  const int wid = tid >> 6, lane = tid & 63;
  const int wm = (wid >> 1) * WM, wn = (wid & 1) * 64;
  const int lr = lane & 15, q = lane >> 4;
  const int g16 = ((lane & 7) ^ ((lane >> 3) & 7)) * 16;
  const int rl = lr & 7;
  const int rb0 = (((2 * q) ^ rl)) * 16;
  const int rb1 = (((2 * q + 1) ^ rl)) * 16;

  f32x4 acc[MFR][4] = {};
  const int NT = K >> 7;

  for (int t = 0; t < NT; ++t) {
    __syncthreads();
    const int k0 = t << 7;
    #pragma unroll
    for (int i = 0; i < MFR; ++i) {
      const int rr = (i * 4 + wid) * 8 + (lane >> 3);
      __builtin_amdgcn_global_load_lds(
          (const AS1 void*)(Ag + (size_t)rr * lda + k0 + g16),
          (AS3 void*)(Asm + (i * 4 + wid) * 1024), 16, 0, 0);
    }
    #pragma unroll
    for (int i = 0; i < 4; ++i) {
      const int rr = (i * 4 + wid) * 8 + (lane >> 3);
      __builtin_amdgcn_global_load_lds(
          (const AS1 void*)(Bg + (size_t)rr * ldb + k0 + g16),
          (AS3 void*)(Bsm + (i * 4 + wid) * 1024), 16, 0, 0);
    }
    __syncthreads();  // compiler drains vmcnt(0) before barrier

    i32x8 bf[4], af[MFR];
    #pragma unroll
    for (int n = 0; n < 4; ++n) {
      const unsigned char* rp = Bsm + (wn + n * 16 + lr) * 128;
      *reinterpret_cast<uint4*>(&bf[n]) = *reinterpret_cast<const uint4*>(rp + rb0);
      *(reinterpret_cast<uint4*>(&bf[n]) + 1) = *reinterpret_cast<const uint4*>(rp + rb1);
    }
    #pragma unroll
    for (int mi = 0; mi < MFR; ++mi) {
      const unsigned char* rp = Asm + (wm + mi * 16 + lr) * 128;
      *reinterpret_cast<uint4*>(&af[mi]) = *reinterpret_cast<const uint4*>(rp + rb0);
      *(reinterpret_cast<uint4*>(&af[mi]) + 1) = *reinterpret_cast<const uint4*>(rp + rb1);
    }
    __builtin_amdgcn_s_setprio(1);
    #pragma unroll
    for (int mi = 0; mi < MFR; ++mi)
      #pragma unroll
      for (int n = 0; n < 4; ++n)
        acc[mi][n] = __builtin_amdgcn_mfma_scale_f32_16x16x128_f8f6f4(
            af[mi], bf[n], acc[mi][n], 0, 0, 0, 127, 0, 127);
    __builtin_amdgcn_s_setprio(0);
  }

  const int rg = q * 4;
  if (MODE == 0) {
    unsigned char* Co = (unsigned char*)Cp + (size_t)z * sC;
    float* Dz = denom + (size_t)z * sDen;
    #pragma unroll
    for (int m = 0; m < MFR; ++m) {
      float ev[4][4];
      #pragma unroll
      for (int n = 0; n < 4; ++n) {
        const int col = by * 128 + wn + n * 16 + lr;
        #pragma unroll
        for (int r = 0; r < 4; ++r) {
          int row = bx * MT + wm + m * 16 + rg + r;
          ev[n][r] = __expf(acc[m][n][r] * scale);
          Co[(size_t)row * ldc + col] = f2fp8(ev[n][r]);
        }
      }
      #pragma unroll
      for (int r = 0; r < 4; ++r) {
        float s = (ev[0][r] + ev[1][r]) + (ev[2][r] + ev[3][r]);
        s += __shfl_xor(s, 1); s += __shfl_xor(s, 2);
        s += __shfl_xor(s, 4); s += __shfl_xor(s, 8);
        if (lr == 0) {
          int row = bx * MT + wm + m * 16 + rg + r;
          atomicAdd(&Dz[row], s);
        }
      }
    }
  } else {
    float* Co = (float*)Cp + (size_t)z * sC;
    const float* Rs = resid + (size_t)z * sR;
    const float* Dz = denom + (size_t)z * sDen;
    #pragma unroll
    for (int n = 0; n < 4; ++n) {
      const int col = by * 128 + wn + n * 16 + lr;
      const float dinv = 1.0f / Dz[col];
      #pragma unroll
      for (int m = 0; m < MFR; ++m)
        #pragma unroll
        for (int r = 0; r < 4; ++r) {
          int row = bx * MT + wm + m * 16 + rg + r;
          size_t idx = (size_t)row * ldc + col;
          Co[idx] = acc[m][n][r] * dinv + bias[row] + Rs[idx];
        }
    }
  }
}

extern "C" void kernel_launch(void* const* d_in, const int* in_sizes, int n_in,
                              void* d_out, int out_size, void* d_ws, size_t ws_size,
                              hipStream_t stream) {
  const float* x  = (const float*)d_in[0];
  const float* wq = (const float*)d_in[1];
  const float* bq = (const float*)d_in[2];
  const float* wk = (const float*)d_in[3];
  const float* bk = (const float*)d_in[4];
  const float* wv = (const float*)d_in[5];
  const float* bv = (const float*)d_in[6];
  const float* wp = (const float*)d_in[7];
  const float* bp = (const float*)d_in[8];
  float* out = (float*)d_out;
  char* ws = (char*)d_ws;
  const size_t MB = 1024 * 1024;
  unsigned short* Wq  = (unsigned short*)(ws + 0);
  unsigned short* Wk  = (unsigned short*)(ws + 512 * 1024);
  unsigned short* Wv  = (unsigned short*)(ws + 1 * MB);
  unsigned short* Wp  = (unsigned short*)(ws + MB + 512 * 1024);
  unsigned short* Xt  = (unsigned short*)(ws + 2 * MB);   // [B,N,C] bf16
  unsigned char*  Qb8 = (unsigned char*)(ws + 18 * MB);   // [B,N,C] fp8
  unsigned char*  Kb8 = (unsigned char*)(ws + 26 * MB);   // [B,N,C] fp8
  unsigned short* Vb  = (unsigned short*)(ws + 34 * MB);  // [B,N,C] bf16
  unsigned char*  PVt = (unsigned char*)(ws + 50 * MB);   // [B,C,N] fp8
  float* denom = (float*)(ws + 58 * MB);                  // [B,N] f32
  unsigned char*  P8  = (unsigned char*)(ws + 59 * MB);   // E fp8 [N,N] x (1|4)
  const long NCe = (long)N_DIM * C_DIM;
  const long NNe = (long)N_DIM * N_DIM;
  const long PVe = (long)C_DIM * N_DIM;
  const float rs = 0.044194173824159216f;  // 1/sqrt(512)
  const bool big = ws_size >= 59 * MB + 4 * (size_t)N_DIM * N_DIM;

  cvt_weights<<<dim3((C_DIM * C_DIM + 255) / 256), 256, 0, stream>>>(
      wq, wk, wv, wp, Wq, Wk, Wv, Wp);
  transpose_x<<<dim3(N_DIM / 32, C_DIM / 32, B_DIM), dim3(32, 8), 0, stream>>>(x, Xt);
  gemm_qkv<<<dim3(32, 4, 12), 256, 0, stream>>>(
      Xt, Wq, Wk, Wv, bq, bk, bv, Qb8, Kb8, Vb);
  gemm_pvt<<<dim3(4, 32, 4), 256, 0, stream>>>(Wp, Vb, PVt);
  zero_buf<<<dim3(B_DIM * N_DIM / 256), 256, 0, stream>>>(denom, B_DIM * N_DIM);

  if (big) {
    // E = exp(rs * Q.K^T) (fp8); denom[n] += rowsum (f32, pre-rounding)
    gemm_mx<4, 0, 32, 32><<<dim3(32, 32, 4), 256, 0, stream>>>(
        Qb8, NCe, Kb8, NCe, P8, NNe, C_DIM, C_DIM, C_DIM, N_DIM, rs,
        nullptr, denom, N_DIM, nullptr, 0);
    // out[o,n] = (sum_j PVt[o,j] E[n,j]) / denom[n] + bp[o] + x[o,n]
    gemm_mx<2, 1, 8, 32><<<dim3(8, 32, 4), 256, 0, stream>>>(
        PVt, PVe, P8, NNe, out, NCe, N_DIM, N_DIM, N_DIM, N_DIM, 1.0f,
        bp, denom, N_DIM, x, NCe);
  } else {
    for (int b = 0; b < B_DIM; ++b) {
      gemm_mx<4, 0, 32, 32><<<dim3(32, 32, 1), 256, 0, stream>>>(
          Qb8 + (size_t)b * NCe, 0, Kb8 + (size_t)b * NCe, 0, P8, 0,
          C_DIM, C_DIM, C_DIM, N_DIM, rs, nullptr, denom + (size_t)b * N_DIM, 0,
          nullptr, 0);
      gemm_mx<2, 1, 8, 32><<<dim3(8, 32, 1), 256, 0, stream>>>(
          PVt + (size_t)b * PVe, 0, P8, 0, (void*)(out + (size_t)b * NCe), 0,
          N_DIM, N_DIM, N_DIM, N_DIM, 1.0f, bp, denom + (size_t)b * N_DIM, 0,
          x + (size_t)b * NCe, 0);
    }
  }
}

// Round 14
// 188.436 us; speedup vs baseline: 1.5343x; 1.5343x over previous
//
#include <hip/hip_runtime.h>
#include <hip/hip_bf16.h>
#include <stdint.h>

// B=4, C=512, H=W=64 -> N=4096. Channel-first x [B,C,N].
#define C_DIM 512
#define N_DIM 4096
#define B_DIM 4

typedef __bf16 bf16x8 __attribute__((ext_vector_type(8)));
typedef float f32x4 __attribute__((ext_vector_type(4)));
typedef int i32x8 __attribute__((ext_vector_type(8)));
#define AS1 __attribute__((address_space(1)))
#define AS3 __attribute__((address_space(3)))

static __device__ __forceinline__ unsigned short f2bf(float x) {
  unsigned u = __float_as_uint(x);
  unsigned r = (u + 0x7fffu + ((u >> 16) & 1u)) >> 16;
  return (unsigned short)r;
}
static __device__ __forceinline__ unsigned char f2fp8(float x) {
  return (unsigned char)__builtin_amdgcn_cvt_pk_fp8_f32(x, x, 0, false);
}

__global__ __launch_bounds__(256) void cvt_weights(
    const float* __restrict__ w0, const float* __restrict__ w1,
    const float* __restrict__ w2, const float* __restrict__ w3,
    unsigned short* __restrict__ o0, unsigned short* __restrict__ o1,
    unsigned short* __restrict__ o2, unsigned short* __restrict__ o3) {
  int i = blockIdx.x * blockDim.x + threadIdx.x;
  if (i < C_DIM * C_DIM) {
    o0[i] = f2bf(w0[i]); o1[i] = f2bf(w1[i]);
    o2[i] = f2bf(w2[i]); o3[i] = f2bf(w3[i]);
  }
}

// x [B,C,N] f32 -> Xt [B,N,C] bf16
__global__ __launch_bounds__(256) void transpose_x(
    const float* __restrict__ x, unsigned short* __restrict__ Xt) {
  __shared__ float t[32][33];
  const int b = blockIdx.z;
  const float* xb = x + (size_t)b * C_DIM * N_DIM;
  unsigned short* xtb = Xt + (size_t)b * N_DIM * C_DIM;
  const int n0 = blockIdx.x * 32, c0 = blockIdx.y * 32;
  const int tx = threadIdx.x, ty = threadIdx.y;
  #pragma unroll
  for (int i = ty; i < 32; i += 8)
    t[i][tx] = xb[(size_t)(c0 + i) * N_DIM + n0 + tx];
  __syncthreads();
  #pragma unroll
  for (int i = ty; i < 32; i += 8)
    xtb[(size_t)(n0 + i) * C_DIM + c0 + tx] = f2bf(t[tx][i]);
}

__global__ __launch_bounds__(256) void zero_buf(float* __restrict__ p, int n) {
  int i = blockIdx.x * 256 + threadIdx.x;
  if (i < n) p[i] = 0.f;
}

// ---------------- 128^2-tile 2-phase NT GEMM body (bf16 inputs) ------------
template<int BIAS, int OUT8>
__device__ __forceinline__ void gemm128_body(
    unsigned short* As, unsigned short* Bs,
    const unsigned short* __restrict__ A, const unsigned short* __restrict__ B,
    void* __restrict__ Cv, int K, int ldc,
    const float* __restrict__ bias, int bx, int by) {
  const int tid = threadIdx.x;
  const int wid = tid >> 6, lane = tid & 63;
  const int wm = (wid >> 1) * 64, wn = (wid & 1) * 64;
  f32x4 acc[4][4] = {};
  const size_t rowA0 = (size_t)bx * 128;
  const size_t rowB0 = (size_t)by * 128;
  const int sgrp = wid * 2;
  const int r0 = (sgrp * 64 + lane) >> 2;
  const int r1 = ((sgrp + 1) * 64 + lane) >> 2;
  const int cc = ((lane & 3) ^ ((lane >> 3) & 3)) * 8;
  const int lr = lane & 15;
  const int koff = (((lane >> 4) ^ ((lr >> 1) & 3))) * 8;

  for (int k0 = 0; k0 < K; k0 += 32) {
    __syncthreads();
    __builtin_amdgcn_global_load_lds(
        (const AS1 void*)(A + (rowA0 + r0) * K + k0 + cc),
        (AS3 void*)(As + sgrp * 512), 16, 0, 0);
    __builtin_amdgcn_global_load_lds(
        (const AS1 void*)(A + (rowA0 + r1) * K + k0 + cc),
        (AS3 void*)(As + (sgrp + 1) * 512), 16, 0, 0);
    __builtin_amdgcn_global_load_lds(
        (const AS1 void*)(B + (rowB0 + r0) * K + k0 + cc),
        (AS3 void*)(Bs + sgrp * 512), 16, 0, 0);
    __builtin_amdgcn_global_load_lds(
        (const AS1 void*)(B + (rowB0 + r1) * K + k0 + cc),
        (AS3 void*)(Bs + (sgrp + 1) * 512), 16, 0, 0);
    __syncthreads();
    bf16x8 af[4], bf[4];
    #pragma unroll
    for (int m = 0; m < 4; ++m)
      af[m] = *reinterpret_cast<const bf16x8*>(&As[(wm + m * 16 + lr) * 32 + koff]);
    #pragma unroll
    for (int n = 0; n < 4; ++n)
      bf[n] = *reinterpret_cast<const bf16x8*>(&Bs[(wn + n * 16 + lr) * 32 + koff]);
    #pragma unroll
    for (int m = 0; m < 4; ++m)
      #pragma unroll
      for (int n = 0; n < 4; ++n)
        acc[m][n] = __builtin_amdgcn_mfma_f32_16x16x32_bf16(af[m], bf[n], acc[m][n], 0, 0, 0);
  }

  const int rg = (lane >> 4) * 4;
  #pragma unroll
  for (int m = 0; m < 4; ++m) {
    #pragma unroll
    for (int n = 0; n < 4; ++n) {
      const int col = (int)rowB0 + wn + n * 16 + lr;
      #pragma unroll
      for (int r = 0; r < 4; ++r) {
        int row = (int)rowA0 + wm + m * 16 + rg + r;
        float v = acc[m][n][r];
        if (BIAS == 1) v += bias[col];
        if (OUT8)
          ((unsigned char*)Cv)[(size_t)row * ldc + col] = f2fp8(v);
        else
          ((unsigned short*)Cv)[(size_t)row * ldc + col] = f2bf(v);
      }
    }
  }
}

// merged Q,K,V projections: grid (32, 4, 12); z = wsel + 3*batch
__global__ __launch_bounds__(256, 2) void gemm_qkv(
    const unsigned short* __restrict__ Xt,
    const unsigned short* __restrict__ Wq, const unsigned short* __restrict__ Wk,
    const unsigned short* __restrict__ Wv,
    const float* __restrict__ bq, const float* __restrict__ bk,
    const float* __restrict__ bv,
    unsigned char* __restrict__ Qb, unsigned char* __restrict__ Kb,
    unsigned short* __restrict__ Vb) {
  __shared__ unsigned short As[4096], Bs[4096];
  const long NCe = (long)N_DIM * C_DIM;
  const int z = blockIdx.z;
  const int wsel = z % 3, bat = z / 3;
  const unsigned short* Xz = Xt + (size_t)bat * NCe;
  if (wsel == 0) {
    gemm128_body<1, 1>(As, Bs, Xz, Wq, Qb + (size_t)bat * NCe, C_DIM, C_DIM,
                       bq, blockIdx.x, blockIdx.y);
  } else if (wsel == 1) {
    gemm128_body<1, 1>(As, Bs, Xz, Wk, Kb + (size_t)bat * NCe, C_DIM, C_DIM,
                       bk, blockIdx.x, blockIdx.y);
  } else {
    gemm128_body<1, 0>(As, Bs, Xz, Wv, Vb + (size_t)bat * NCe, C_DIM, C_DIM,
                       bv, blockIdx.x, blockIdx.y);
  }
}

// PVt[o,j] = sum_c Wp[o,c] V[j,c] -> fp8; grid (4, 32, 4)
__global__ __launch_bounds__(256, 2) void gemm_pvt(
    const unsigned short* __restrict__ Wp, const unsigned short* __restrict__ Vb,
    unsigned char* __restrict__ PVt) {
  __shared__ unsigned short As[4096], Bs[4096];
  const long NCe = (long)N_DIM * C_DIM;
  const long PVe = (long)C_DIM * N_DIM;
  const int z = blockIdx.z;
  gemm128_body<0, 1>(As, Bs, Wp, Vb + (size_t)z * NCe, PVt + (size_t)z * PVe,
                     C_DIM, N_DIM, nullptr, blockIdx.x, blockIdx.y);
}

// ---------------- MX-fp8 NT GEMM (m97 structure, K-step 128) ----------------
// A,B fp8 e4m3 row-major NT. 256 thr = 4 waves (2x2). M-tile = MFR*32
// (per-wave MFR m-frags x 64 cols), B-tile 128. acc[MFR][4].
// mfma_scale_f32_16x16x128_f8f6f4, scale=1.0 (e8m0 127) = exact fp8 math at
// 2x bf16 rate. Single-buffered 2-phase (m97/m114 cross-block overlap).
// __launch_bounds__(256,3): R12-proven no-spill (R13's (256,4) capped the
// unified VGPR+AGPR file at 128/wave -> acc spilled -> 577MB scratch writes,
// 2.7x slower. acc[4][4]=64 AGPR + frags 64 VGPR needs the 160-reg budget).
// Swizzle: phys 16B slot p of row r holds global slot p ^ (r&7); staged via
// pre-swizzled global source (linear gload_lds dest). Frag reads land
// directly in i32x8 halves (no VALU repack).
// A-frag: lane l holds row l&15, k = (l>>4)*32..+31 (two b128) [verified R12].
// MODE 0: store fp8 exp(scale*acc); f32 rowsums -> atomicAdd denom[row].
// MODE 1: store f32 acc/denom[col] + bias[row] + resid  (final output).
template<int MFR, int MODE, int GX, int GY>
__global__ __launch_bounds__(256, 3) void gemm_mx(
    const unsigned char* __restrict__ A, long sA,
    const unsigned char* __restrict__ B, long sB,
    void* __restrict__ Cp, long sC,
    int K, int lda, int ldb, int ldc, float scale,
    const float* __restrict__ bias,
    float* __restrict__ denom, long sDen,
    const float* __restrict__ resid, long sR) {
  constexpr int MT = MFR * 32;           // block M-tile rows
  constexpr int WM = MFR * 16;           // per-wave M rows
  __shared__ unsigned char Asm[MT * 128], Bsm[16384];

  // XCD-aware bijective block swizzle (nwg % 8 == 0 at all call sites)
  int flat = blockIdx.x + GX * (blockIdx.y + GY * blockIdx.z);
  const int nwg = GX * GY * gridDim.z;
  flat = (flat & 7) * (nwg >> 3) + (flat >> 3);
  const int bx = flat & (GX - 1);
  const int by = (flat / GX) & (GY - 1);
  const int z  = flat / (GX * GY);

  const unsigned char* Ag = A + (size_t)z * sA + (size_t)bx * MT * lda;
  const unsigned char* Bg = B + (size_t)z * sB + (size_t)by * 128 * ldb;
  const int tid = threadIdx.x;
  const int wid = tid >> 6, lane = tid & 63;
  const int wm = (wid >> 1) * WM, wn = (wid & 1) * 64;
  const int lr = lane & 15, q = lane >> 4;
  const int g16 = ((lane & 7) ^ ((lane >> 3) & 7)) * 16;
  const int rl = lr & 7;
  const int rb0 = (((2 * q) ^ rl)) * 16;
  const int rb1 = (((2 * q + 1) ^ rl)) * 16;

  f32x4 acc[MFR][4] = {};
  const int NT = K >> 7;

  for (int t = 0; t < NT; ++t) {
    __syncthreads();
    const int k0 = t << 7;
    #pragma unroll
    for (int i = 0; i < MFR; ++i) {
      const int rr = (i * 4 + wid) * 8 + (lane >> 3);
      __builtin_amdgcn_global_load_lds(
          (const AS1 void*)(Ag + (size_t)rr * lda + k0 + g16),
          (AS3 void*)(Asm + (i * 4 + wid) * 1024), 16, 0, 0);
    }
    #pragma unroll
    for (int i = 0; i < 4; ++i) {
      const int rr = (i * 4 + wid) * 8 + (lane >> 3);
      __builtin_amdgcn_global_load_lds(
          (const AS1 void*)(Bg + (size_t)rr * ldb + k0 + g16),
          (AS3 void*)(Bsm + (i * 4 + wid) * 1024), 16, 0, 0);
    }
    __syncthreads();  // compiler drains vmcnt(0) before barrier

    i32x8 bf[4], af[MFR];
    #pragma unroll
    for (int n = 0; n < 4; ++n) {
      const unsigned char* rp = Bsm + (wn + n * 16 + lr) * 128;
      *reinterpret_cast<uint4*>(&bf[n]) = *reinterpret_cast<const uint4*>(rp + rb0);
      *(reinterpret_cast<uint4*>(&bf[n]) + 1) = *reinterpret_cast<const uint4*>(rp + rb1);
    }
    #pragma unroll
    for (int mi = 0; mi < MFR; ++mi) {
      const unsigned char* rp = Asm + (wm + mi * 16 + lr) * 128;
      *reinterpret_cast<uint4*>(&af[mi]) = *reinterpret_cast<const uint4*>(rp + rb0);
      *(reinterpret_cast<uint4*>(&af[mi]) + 1) = *reinterpret_cast<const uint4*>(rp + rb1);
    }
    __builtin_amdgcn_s_setprio(1);
    #pragma unroll
    for (int mi = 0; mi < MFR; ++mi)
      #pragma unroll
      for (int n = 0; n < 4; ++n)
        acc[mi][n] = __builtin_amdgcn_mfma_scale_f32_16x16x128_f8f6f4(
            af[mi], bf[n], acc[mi][n], 0, 0, 0, 127, 0, 127);
    __builtin_amdgcn_s_setprio(0);
  }

  const int rg = q * 4;
  if (MODE == 0) {
    unsigned char* Co = (unsigned char*)Cp + (size_t)z * sC;
    float* Dz = denom + (size_t)z * sDen;
    #pragma unroll
    for (int m = 0; m < MFR; ++m) {
      float ev[4][4];
      #pragma unroll
      for (int n = 0; n < 4; ++n) {
        const int col = by * 128 + wn + n * 16 + lr;
        #pragma unroll
        for (int r = 0; r < 4; ++r) {
          int row = bx * MT + wm + m * 16 + rg + r;
          ev[n][r] = __expf(acc[m][n][r] * scale);
          Co[(size_t)row * ldc + col] = f2fp8(ev[n][r]);
        }
      }
      #pragma unroll
      for (int r = 0; r < 4; ++r) {
        float s = (ev[0][r] + ev[1][r]) + (ev[2][r] + ev[3][r]);
        s += __shfl_xor(s, 1); s += __shfl_xor(s, 2);
        s += __shfl_xor(s, 4); s += __shfl_xor(s, 8);
        if (lr == 0) {
          int row = bx * MT + wm + m * 16 + rg + r;
          atomicAdd(&Dz[row], s);
        }
      }
    }
  } else {
    float* Co = (float*)Cp + (size_t)z * sC;
    const float* Rs = resid + (size_t)z * sR;
    const float* Dz = denom + (size_t)z * sDen;
    #pragma unroll
    for (int n = 0; n < 4; ++n) {
      const int col = by * 128 + wn + n * 16 + lr;
      const float dinv = 1.0f / Dz[col];
      #pragma unroll
      for (int m = 0; m < MFR; ++m)
        #pragma unroll
        for (int r = 0; r < 4; ++r) {
          int row = bx * MT + wm + m * 16 + rg + r;
          size_t idx = (size_t)row * ldc + col;
          Co[idx] = acc[m][n][r] * dinv + bias[row] + Rs[idx];
        }
    }
  }
}

extern "C" void kernel_launch(void* const* d_in, const int* in_sizes, int n_in,
                              void* d_out, int out_size, void* d_ws, size_t ws_size,
                              hipStream_t stream) {
  const float* x  = (const float*)d_in[0];
  const float* wq = (const float*)d_in[1];
  const float* bq = (const float*)d_in[2];
  const float* wk = (const float*)d_in[3];
  const float* bk = (const float*)d_in[4];
  const float* wv = (const float*)d_in[5];
  const float* bv = (const float*)d_in[6];
  const float* wp = (const float*)d_in[7];
  const float* bp = (const float*)d_in[8];
  float* out = (float*)d_out;
  char* ws = (char*)d_ws;
  const size_t MB = 1024 * 1024;
  unsigned short* Wq  = (unsigned short*)(ws + 0);
  unsigned short* Wk  = (unsigned short*)(ws + 512 * 1024);
  unsigned short* Wv  = (unsigned short*)(ws + 1 * MB);
  unsigned short* Wp  = (unsigned short*)(ws + MB + 512 * 1024);
  unsigned short* Xt  = (unsigned short*)(ws + 2 * MB);   // [B,N,C] bf16
  unsigned char*  Qb8 = (unsigned char*)(ws + 18 * MB);   // [B,N,C] fp8
  unsigned char*  Kb8 = (unsigned char*)(ws + 26 * MB);   // [B,N,C] fp8
  unsigned short* Vb  = (unsigned short*)(ws + 34 * MB);  // [B,N,C] bf16
  unsigned char*  PVt = (unsigned char*)(ws + 50 * MB);   // [B,C,N] fp8
  float* denom = (float*)(ws + 58 * MB);                  // [B,N] f32
  unsigned char*  P8  = (unsigned char*)(ws + 59 * MB);   // E fp8 [N,N] x (1|4)
  const long NCe = (long)N_DIM * C_DIM;
  const long NNe = (long)N_DIM * N_DIM;
  const long PVe = (long)C_DIM * N_DIM;
  const float rs = 0.044194173824159216f;  // 1/sqrt(512)
  const bool big = ws_size >= 59 * MB + 4 * (size_t)N_DIM * N_DIM;

  cvt_weights<<<dim3((C_DIM * C_DIM + 255) / 256), 256, 0, stream>>>(
      wq, wk, wv, wp, Wq, Wk, Wv, Wp);
  transpose_x<<<dim3(N_DIM / 32, C_DIM / 32, B_DIM), dim3(32, 8), 0, stream>>>(x, Xt);
  gemm_qkv<<<dim3(32, 4, 12), 256, 0, stream>>>(
      Xt, Wq, Wk, Wv, bq, bk, bv, Qb8, Kb8, Vb);
  gemm_pvt<<<dim3(4, 32, 4), 256, 0, stream>>>(Wp, Vb, PVt);
  zero_buf<<<dim3(B_DIM * N_DIM / 256), 256, 0, stream>>>(denom, B_DIM * N_DIM);

  if (big) {
    // E = exp(rs * Q.K^T) (fp8); denom[n] += rowsum (f32, pre-rounding)
    gemm_mx<4, 0, 32, 32><<<dim3(32, 32, 4), 256, 0, stream>>>(
        Qb8, NCe, Kb8, NCe, P8, NNe, C_DIM, C_DIM, C_DIM, N_DIM, rs,
        nullptr, denom, N_DIM, nullptr, 0);
    // out[o,n] = (sum_j PVt[o,j] E[n,j]) / denom[n] + bp[o] + x[o,n]
    gemm_mx<2, 1, 8, 32><<<dim3(8, 32, 4), 256, 0, stream>>>(
        PVt, PVe, P8, NNe, out, NCe, N_DIM, N_DIM, N_DIM, N_DIM, 1.0f,
        bp, denom, N_DIM, x, NCe);
  } else {
    for (int b = 0; b < B_DIM; ++b) {
      gemm_mx<4, 0, 32, 32><<<dim3(32, 32, 1), 256, 0, stream>>>(
          Qb8 + (size_t)b * NCe, 0, Kb8 + (size_t)b * NCe, 0, P8, 0,
          C_DIM, C_DIM, C_DIM, N_DIM, rs, nullptr, denom + (size_t)b * N_DIM, 0,
          nullptr, 0);
      gemm_mx<2, 1, 8, 32><<<dim3(8, 32, 1), 256, 0, stream>>>(
          PVt + (size_t)b * PVe, 0, P8, 0, (void*)(out + (size_t)b * NCe), 0,
          N_DIM, N_DIM, N_DIM, N_DIM, 1.0f, bp, denom + (size_t)b * N_DIM, 0,
          x + (size_t)b * NCe, 0);
    }
  }
}